// Round 1
// baseline (403.064 us; speedup 1.0000x reference)
//
#include <hip/hip_runtime.h>
#include <hip/hip_bf16.h>
#include <stdint.h>

typedef unsigned short u16;
typedef __attribute__((ext_vector_type(8))) __bf16 bf16x8;
typedef __attribute__((ext_vector_type(4))) float f32x4;
typedef __attribute__((ext_vector_type(8))) u16 u16x8;
typedef __attribute__((ext_vector_type(4))) u16 u16x4;

typedef const __attribute__((address_space(1))) void GV;
typedef __attribute__((address_space(3))) void LV;

__device__ __forceinline__ u16 f2bf(float f) {
  union { float f; uint32_t u; } c; c.f = f;
  uint32_t u = c.u;
  u = u + 0x7FFFu + ((u >> 16) & 1u);
  return (u16)(u >> 16);
}

#define BM 128
#define BN 128
#define BK 32

// C[M,N] = A[M,K] (row-major, lda) * B[N,K]^T (row-major, ldb); bf16 inputs (as u16).
// MODE 0: write fp32 C (ldc, batch stride sCb)
// MODE 1: QKV split epilogue: col<1024 -> Qo, <2048 -> Ko, else -> Vo (bf16, +bias)
template<int MODE>
__global__ __launch_bounds__(256) void gemm_bt(
    const u16* __restrict__ A, const u16* __restrict__ B,
    int K, int lda, int ldb,
    long sAb, long sBb,
    float* __restrict__ Cf, int ldc, long sCb,
    u16* __restrict__ Qo, u16* __restrict__ Ko, u16* __restrict__ Vo,
    const float* __restrict__ bias)
{
  const int tid = threadIdx.x;
  const int lane = tid & 63;
  const int w = tid >> 6;
  const int wr = w >> 1, wc = w & 1;
  const int bz = blockIdx.z;
  const u16* Ab = A + (long)bz * sAb;
  const u16* Bb = B + (long)bz * sBb;
  const int row0 = blockIdx.y * BM;
  const int col0 = blockIdx.x * BN;

  __shared__ u16 As[BM][BK];
  __shared__ u16 Bs[BN][BK];

  f32x4 acc[4][4];
#pragma unroll
  for (int i = 0; i < 4; ++i)
#pragma unroll
    for (int j = 0; j < 4; ++j) acc[i][j] = (f32x4)(0.f);

  const int srow = w * 16 + (lane >> 2);   // staging row within tile (per wave-issue)
  const int scol = (lane & 3) * 8;         // staging col (8 bf16 = 16B)
  const int fr = lane & 15;                // fragment row/col
  const int kq = (lane >> 4) * 8;          // fragment k base

  const int nkt = K / BK;
  for (int kt = 0; kt < nkt; ++kt) {
    const int kb = kt * BK;
    __syncthreads();
#pragma unroll
    for (int j = 0; j < 2; ++j) {
      const u16* g = Ab + (long)(row0 + srow + j * 64) * lda + (kb + scol);
      __builtin_amdgcn_global_load_lds((GV*)g, (LV*)(&As[w * 16 + j * 64][0]), 16, 0, 0);
    }
#pragma unroll
    for (int j = 0; j < 2; ++j) {
      const u16* g = Bb + (long)(col0 + srow + j * 64) * ldb + (kb + scol);
      __builtin_amdgcn_global_load_lds((GV*)g, (LV*)(&Bs[w * 16 + j * 64][0]), 16, 0, 0);
    }
    asm volatile("s_waitcnt vmcnt(0)" ::: "memory");
    __syncthreads();

    bf16x8 af[4], bfr[4];
#pragma unroll
    for (int mi = 0; mi < 4; ++mi)
      af[mi] = *(const bf16x8*)(&As[wr * 64 + mi * 16 + fr][kq]);
#pragma unroll
    for (int ni = 0; ni < 4; ++ni)
      bfr[ni] = *(const bf16x8*)(&Bs[wc * 64 + ni * 16 + fr][kq]);
#pragma unroll
    for (int mi = 0; mi < 4; ++mi)
#pragma unroll
      for (int ni = 0; ni < 4; ++ni)
        acc[mi][ni] = __builtin_amdgcn_mfma_f32_16x16x32_bf16(af[mi], bfr[ni], acc[mi][ni], 0, 0, 0);
  }

  const int cr = (lane >> 4) * 4;
  const int cc = lane & 15;
#pragma unroll
  for (int mi = 0; mi < 4; ++mi) {
#pragma unroll
    for (int ni = 0; ni < 4; ++ni) {
      const int gcol = col0 + wc * 64 + ni * 16 + cc;
#pragma unroll
      for (int r = 0; r < 4; ++r) {
        const int grow = row0 + wr * 64 + mi * 16 + cr + r;
        float v = acc[mi][ni][r];
        if (MODE == 0) {
          Cf[(long)bz * sCb + (long)grow * ldc + gcol] = v;
        } else {
          v += bias[gcol];
          u16 h = f2bf(v);
          if (gcol < 1024)      Qo[(long)grow * 1024 + gcol] = h;
          else if (gcol < 2048) Ko[(long)grow * 1024 + (gcol - 1024)] = h;
          else                  Vo[(long)grow * 1024 + (gcol - 2048)] = h;
        }
      }
    }
  }
}

__global__ __launch_bounds__(256) void f32_to_bf16_vec(const float* __restrict__ in,
                                                       u16* __restrict__ o, long n)
{
  long i = ((long)blockIdx.x * 256 + threadIdx.x) * 4;
  if (i < n) {
    float4 v = *(const float4*)(in + i);
    u16x4 r; r[0] = f2bf(v.x); r[1] = f2bf(v.y); r[2] = f2bf(v.z); r[3] = f2bf(v.w);
    *(u16x4*)(o + i) = r;
  }
}

__global__ void concat_bias(const float* __restrict__ bq, const float* __restrict__ bk,
                            const float* __restrict__ bv, float* __restrict__ b)
{
  int i = blockIdx.x * 256 + threadIdx.x;
  if (i < 1024)      b[i] = bq[i];
  else if (i < 2048) b[i] = bk[i - 1024];
  else if (i < 3072) b[i] = bv[i - 2048];
}

// V [B][2048][1024] bf16 -> Vt [B][1024][2048]
__global__ __launch_bounds__(256) void transpose_bf16(const u16* __restrict__ V,
                                                      u16* __restrict__ Vt)
{
  __shared__ u16 t[32][33];
  const int b = blockIdx.z;
  const u16* Vb = V + (long)b * 2097152;
  u16* Vtb = Vt + (long)b * 2097152;
  const int tx = threadIdx.x & 31, ty = threadIdx.x >> 5;
  const int h0 = blockIdx.x * 32, s0 = blockIdx.y * 32;
#pragma unroll
  for (int i = 0; i < 4; ++i)
    t[ty + i * 8][tx] = Vb[(long)(s0 + ty + i * 8) * 1024 + h0 + tx];
  __syncthreads();
#pragma unroll
  for (int i = 0; i < 4; ++i)
    Vtb[(long)(h0 + ty + i * 8) * 2048 + s0 + tx] = t[tx][ty + i * 8];
}

// one block per row: s = scores*scale + am + pw*pm; softmax; write P bf16
// P written in-place over the score row (row byte stride 8192, data 4096B).
__global__ __launch_bounds__(256) void softmax_rows(
    const float* scores, const float* __restrict__ am,
    const float* __restrict__ pm, const float* __restrict__ pw, u16* P)
{
  const long g = blockIdx.x;
  const int tid = threadIdx.x;
  const int lane = tid & 63;
  const int wv = tid >> 6;
  const float* s = scores + g * 2048;
  const float* a = am + g * 2048;
  const float* p = pm + g * 2048;
  u16* po = (u16*)((char*)P + g * 8192);
  const float wgt = pw[0];

  float sv[8], av[8], pvv[8], v[8];
  *(float4*)&sv[0]  = *(const float4*)(s + tid * 8);
  *(float4*)&sv[4]  = *(const float4*)(s + tid * 8 + 4);
  *(float4*)&av[0]  = *(const float4*)(a + tid * 8);
  *(float4*)&av[4]  = *(const float4*)(a + tid * 8 + 4);
  *(float4*)&pvv[0] = *(const float4*)(p + tid * 8);
  *(float4*)&pvv[4] = *(const float4*)(p + tid * 8 + 4);

  float mx = -3.0e38f;
#pragma unroll
  for (int i = 0; i < 8; ++i) {
    v[i] = fmaf(sv[i], 0.03125f, fmaf(wgt, pvv[i], av[i]));
    mx = fmaxf(mx, v[i]);
  }
#pragma unroll
  for (int off = 32; off >= 1; off >>= 1) mx = fmaxf(mx, __shfl_xor(mx, off, 64));
  __shared__ float rmax[4], rsum[4];
  if (lane == 0) rmax[wv] = mx;
  __syncthreads();
  mx = fmaxf(fmaxf(rmax[0], rmax[1]), fmaxf(rmax[2], rmax[3]));

  float sum = 0.f;
#pragma unroll
  for (int i = 0; i < 8; ++i) { v[i] = __expf(v[i] - mx); sum += v[i]; }
#pragma unroll
  for (int off = 32; off >= 1; off >>= 1) sum += __shfl_xor(sum, off, 64);
  if (lane == 0) rsum[wv] = sum;
  __syncthreads();
  sum = rsum[0] + rsum[1] + rsum[2] + rsum[3];
  const float inv = 1.0f / sum;

  u16x8 o;
#pragma unroll
  for (int i = 0; i < 8; ++i) o[i] = f2bf(v[i] * inv);
  *(u16x8*)(po + tid * 8) = o;
}

extern "C" void kernel_launch(void* const* d_in, const int* in_sizes, int n_in,
                              void* d_out, int out_size, void* d_ws, size_t ws_size,
                              hipStream_t stream) {
  const float* hs = (const float*)d_in[0];
  const float* am = (const float*)d_in[1];
  const float* pm = (const float*)d_in[2];
  const float* Wq = (const float*)d_in[3];
  const float* bq = (const float*)d_in[4];
  const float* Wk = (const float*)d_in[5];
  const float* bk = (const float*)d_in[6];
  const float* Wv = (const float*)d_in[7];
  const float* bv = (const float*)d_in[8];
  const float* pw = (const float*)d_in[9];
  float* out = (float*)d_out;

  char* w = (char*)d_ws;
  u16* X      = (u16*)(w);                    // 16,777,216 B  (reused as Vt later)
  u16* Wqkv   = (u16*)(w + 16777216);         //  6,291,456 B
  float* bias = (float*)(w + 23068672);       //     12,288 B (pad to 16K)
  u16* Qb     = (u16*)(w + 23085056);         // 16,777,216 B
  u16* Kb     = (u16*)(w + 39862272);         // 16,777,216 B
  u16* Vb     = (u16*)(w + 56639488);         // 16,777,216 B
  float* sc   = (float*)(w + 73416704);       // 67,108,864 B (P bf16 in-place)
  u16* Vt     = X;                            // X dead after GEMM1
  u16* P      = (u16*)sc;

  // converts
  hipLaunchKernelGGL(f32_to_bf16_vec, dim3(8192), dim3(256), 0, stream, hs, X, 8388608L);
  hipLaunchKernelGGL(f32_to_bf16_vec, dim3(1024), dim3(256), 0, stream, Wq, Wqkv, 1048576L);
  hipLaunchKernelGGL(f32_to_bf16_vec, dim3(1024), dim3(256), 0, stream, Wk, Wqkv + 1048576, 1048576L);
  hipLaunchKernelGGL(f32_to_bf16_vec, dim3(1024), dim3(256), 0, stream, Wv, Wqkv + 2097152, 1048576L);
  hipLaunchKernelGGL(concat_bias, dim3(12), dim3(256), 0, stream, bq, bk, bv, bias);

  // GEMM1: X[8192,1024] @ Wqkv[3072,1024]^T -> Q,K,V bf16
  hipLaunchKernelGGL((gemm_bt<1>), dim3(24, 64, 1), dim3(256), 0, stream,
                     X, Wqkv, 1024, 1024, 1024, 0L, 0L,
                     (float*)nullptr, 0, 0L, Qb, Kb, Vb, bias);

  // V -> Vt
  hipLaunchKernelGGL(transpose_bf16, dim3(32, 64, 4), dim3(256), 0, stream, Vb, Vt);

  // GEMM2 (batched): scores[b] = Q[b] @ K[b]^T  (fp32)
  hipLaunchKernelGGL((gemm_bt<0>), dim3(16, 16, 4), dim3(256), 0, stream,
                     Qb, Kb, 1024, 1024, 1024, 2097152L, 2097152L,
                     sc, 2048, 4194304L,
                     (u16*)nullptr, (u16*)nullptr, (u16*)nullptr, (const float*)nullptr);

  // softmax rows (scale + masks fused), P bf16 in-place
  hipLaunchKernelGGL(softmax_rows, dim3(8192), dim3(256), 0, stream, sc, am, pm, pw, P);

  // GEMM3 (batched): out[b] = P[b] @ Vt[b]^T  (fp32)
  hipLaunchKernelGGL((gemm_bt<0>), dim3(8, 16, 4), dim3(256), 0, stream,
                     P, Vt, 2048, 4096, 2048, 8388608L, 2097152L,
                     out, 1024, 2097152L,
                     (u16*)nullptr, (u16*)nullptr, (u16*)nullptr, (const float*)nullptr);
}

// Round 4
// 379.770 us; speedup vs baseline: 1.0613x; 1.0613x over previous
//
#include <hip/hip_runtime.h>
#include <hip/hip_bf16.h>
#include <stdint.h>

typedef unsigned short u16;
typedef __attribute__((ext_vector_type(8))) __bf16 bf16x8;
typedef __attribute__((ext_vector_type(4))) float f32x4;
typedef __attribute__((ext_vector_type(8))) u16 u16x8;
typedef __attribute__((ext_vector_type(4))) u16 u16x4;

typedef const __attribute__((address_space(1))) void GV;
typedef __attribute__((address_space(3))) void LV;

__device__ __forceinline__ u16 f2bf(float f) {
  union { float f; uint32_t u; } c; c.f = f;
  uint32_t u = c.u;
  u = u + 0x7FFFu + ((u >> 16) & 1u);
  return (u16)(u >> 16);
}

#define BM 128
#define BN 128
#define BK 32

// C[M,N] = A[M,K] (row-major, lda) * B[N,K]^T (row-major, ldb); bf16 inputs (as u16).
// 2-phase double-buffered pipeline (T3-minimum) + both-sides LDS slot swizzle (T2)
// + XCD-aware block swizzle (T1; requires gridX*gridY % 8 == 0).
// MODE 0: write fp32 C (ldc, batch stride sCb)
// MODE 1: QKV split epilogue: col<1024 -> Qo, <2048 -> Ko, else -> Vo (bf16, +bias)
template<int MODE>
__global__ __launch_bounds__(256) void gemm_bt(
    const u16* __restrict__ A, const u16* __restrict__ B,
    int K, int lda, int ldb,
    long sAb, long sBb,
    float* __restrict__ Cf, int ldc, long sCb,
    u16* __restrict__ Qo, u16* __restrict__ Ko, u16* __restrict__ Vo,
    const float* __restrict__ bias)
{
  const int tid = threadIdx.x;
  const int lane = tid & 63;
  const int w = tid >> 6;
  const int wr = w >> 1, wc = w & 1;
  const int bz = blockIdx.z;

  // T1: bijective XCD swizzle over the x-y grid (nwg % 8 == 0 for all our grids)
  const int nwg = gridDim.x * gridDim.y;
  const int wg  = blockIdx.y * gridDim.x + blockIdx.x;
  const int cpx = nwg >> 3;
  const int swg = (wg & 7) * cpx + (wg >> 3);
  const int bx  = swg % gridDim.x;
  const int by  = swg / gridDim.x;

  const u16* Ab = A + (long)bz * sAb;
  const u16* Bb = B + (long)bz * sBb;
  const int row0 = by * BM;
  const int col0 = bx * BN;

  __shared__ u16 As[2][BM][BK];
  __shared__ u16 Bs[2][BN][BK];

  f32x4 acc[4][4];
#pragma unroll
  for (int i = 0; i < 4; ++i)
#pragma unroll
    for (int j = 0; j < 4; ++j) acc[i][j] = (f32x4)(0.f);

  // staging: lane l covers LDS row (l>>2), 16B slot (l&3) of each 16-row group.
  // T2 both-sides swizzle: LDS[row][slot] holds global slot (slot ^ ((row>>1)&3)).
  const int srow = w * 16 + (lane >> 2);            // tile row this lane stages
  const int ssw  = (lane >> 3) & 3;                  // ((local row)>>1)&3
  const int scol = (((lane & 3) ^ ssw) * 8);         // pre-swizzled global slot
  const int fr = lane & 15;                          // fragment row
  const int swr = (fr >> 1) & 3;                     // read-side swizzle
  const int rslot = ((lane >> 4) ^ swr) * 8;         // swizzled 16B slot for k-frag

  const int nkt = K / BK;

  // prologue: stage tile 0 into buf 0
  {
#pragma unroll
    for (int j = 0; j < 2; ++j) {
      const u16* g = Ab + (long)(row0 + srow + j * 64) * lda + scol;
      __builtin_amdgcn_global_load_lds((GV*)g, (LV*)(&As[0][w * 16 + j * 64][0]), 16, 0, 0);
    }
#pragma unroll
    for (int j = 0; j < 2; ++j) {
      const u16* g = Bb + (long)(col0 + srow + j * 64) * ldb + scol;
      __builtin_amdgcn_global_load_lds((GV*)g, (LV*)(&Bs[0][w * 16 + j * 64][0]), 16, 0, 0);
    }
  }
  asm volatile("s_waitcnt vmcnt(0)" ::: "memory");
  __syncthreads();

  int cur = 0;
  for (int kt = 0; kt < nkt; ++kt) {
    // issue next tile's loads first (they fly while we compute this tile)
    if (kt + 1 < nkt) {
      const int kb = (kt + 1) * BK;
#pragma unroll
      for (int j = 0; j < 2; ++j) {
        const u16* g = Ab + (long)(row0 + srow + j * 64) * lda + (kb + scol);
        __builtin_amdgcn_global_load_lds((GV*)g, (LV*)(&As[cur ^ 1][w * 16 + j * 64][0]), 16, 0, 0);
      }
#pragma unroll
      for (int j = 0; j < 2; ++j) {
        const u16* g = Bb + (long)(col0 + srow + j * 64) * ldb + (kb + scol);
        __builtin_amdgcn_global_load_lds((GV*)g, (LV*)(&Bs[cur ^ 1][w * 16 + j * 64][0]), 16, 0, 0);
      }
    }

    bf16x8 af[4], bfr[4];
#pragma unroll
    for (int mi = 0; mi < 4; ++mi)
      af[mi] = *(const bf16x8*)(&As[cur][wr * 64 + mi * 16 + fr][rslot]);
#pragma unroll
    for (int ni = 0; ni < 4; ++ni)
      bfr[ni] = *(const bf16x8*)(&Bs[cur][wc * 64 + ni * 16 + fr][rslot]);
#pragma unroll
    for (int mi = 0; mi < 4; ++mi)
#pragma unroll
      for (int ni = 0; ni < 4; ++ni)
        acc[mi][ni] = __builtin_amdgcn_mfma_f32_16x16x32_bf16(af[mi], bfr[ni], acc[mi][ni], 0, 0, 0);

    asm volatile("s_waitcnt vmcnt(0)" ::: "memory");
    __syncthreads();
    cur ^= 1;
  }

  const int cr = (lane >> 4) * 4;
  const int cc = lane & 15;
#pragma unroll
  for (int mi = 0; mi < 4; ++mi) {
#pragma unroll
    for (int ni = 0; ni < 4; ++ni) {
      const int gcol = col0 + wc * 64 + ni * 16 + cc;
#pragma unroll
      for (int r = 0; r < 4; ++r) {
        const int grow = row0 + wr * 64 + mi * 16 + cr + r;
        float v = acc[mi][ni][r];
        if (MODE == 0) {
          Cf[(long)bz * sCb + (long)grow * ldc + gcol] = v;
        } else {
          v += bias[gcol];
          u16 h = f2bf(v);
          if (gcol < 1024)      Qo[(long)grow * 1024 + gcol] = h;
          else if (gcol < 2048) Ko[(long)grow * 1024 + (gcol - 1024)] = h;
          else                  Vo[(long)grow * 1024 + (gcol - 2048)] = h;
        }
      }
    }
  }
}

__global__ __launch_bounds__(256) void f32_to_bf16_vec(const float* __restrict__ in,
                                                       u16* __restrict__ o, long n)
{
  long i = ((long)blockIdx.x * 256 + threadIdx.x) * 4;
  if (i < n) {
    float4 v = *(const float4*)(in + i);
    u16x4 r; r[0] = f2bf(v.x); r[1] = f2bf(v.y); r[2] = f2bf(v.z); r[3] = f2bf(v.w);
    *(u16x4*)(o + i) = r;
  }
}

__global__ void concat_bias(const float* __restrict__ bq, const float* __restrict__ bk,
                            const float* __restrict__ bv, float* __restrict__ b)
{
  int i = blockIdx.x * 256 + threadIdx.x;
  if (i < 1024)      b[i] = bq[i];
  else if (i < 2048) b[i] = bk[i - 1024];
  else if (i < 3072) b[i] = bv[i - 2048];
}

// V [B][2048][1024] bf16 -> Vt [B][1024][2048]
__global__ __launch_bounds__(256) void transpose_bf16(const u16* __restrict__ V,
                                                      u16* __restrict__ Vt)
{
  __shared__ u16 t[32][33];
  const int b = blockIdx.z;
  const u16* Vb = V + (long)b * 2097152;
  u16* Vtb = Vt + (long)b * 2097152;
  const int tx = threadIdx.x & 31, ty = threadIdx.x >> 5;
  const int h0 = blockIdx.x * 32, s0 = blockIdx.y * 32;
#pragma unroll
  for (int i = 0; i < 4; ++i)
    t[ty + i * 8][tx] = Vb[(long)(s0 + ty + i * 8) * 1024 + h0 + tx];
  __syncthreads();
#pragma unroll
  for (int i = 0; i < 4; ++i)
    Vtb[(long)(h0 + ty + i * 8) * 2048 + s0 + tx] = t[tx][ty + i * 8];
}

// one block per row: s = scores*scale + am + pw*pm; softmax; write P bf16
// P written in-place over the score row (row byte stride 8192, data 4096B).
// (Safe in-place: all reads happen before the first barrier; writes after the
//  second — the barriers order the cross-thread overlap.)
__global__ __launch_bounds__(256) void softmax_rows(
    const float* scores, const float* __restrict__ am,
    const float* __restrict__ pm, const float* __restrict__ pw, u16* P)
{
  const long g = blockIdx.x;
  const int tid = threadIdx.x;
  const int lane = tid & 63;
  const int wv = tid >> 6;
  const float* s = scores + g * 2048;
  const float* a = am + g * 2048;
  const float* p = pm + g * 2048;
  u16* po = (u16*)((char*)P + g * 8192);
  const float wgt = pw[0];

  float sv[8], av[8], pvv[8], v[8];
  *(float4*)&sv[0]  = *(const float4*)(s + tid * 8);
  *(float4*)&sv[4]  = *(const float4*)(s + tid * 8 + 4);
  *(float4*)&av[0]  = *(const float4*)(a + tid * 8);
  *(float4*)&av[4]  = *(const float4*)(a + tid * 8 + 4);
  *(float4*)&pvv[0] = *(const float4*)(p + tid * 8);
  *(float4*)&pvv[4] = *(const float4*)(p + tid * 8 + 4);

  float mx = -3.0e38f;
#pragma unroll
  for (int i = 0; i < 8; ++i) {
    v[i] = fmaf(sv[i], 0.03125f, fmaf(wgt, pvv[i], av[i]));
    mx = fmaxf(mx, v[i]);
  }
#pragma unroll
  for (int off = 32; off >= 1; off >>= 1) mx = fmaxf(mx, __shfl_xor(mx, off, 64));
  __shared__ float rmax[4], rsum[4];
  if (lane == 0) rmax[wv] = mx;
  __syncthreads();
  mx = fmaxf(fmaxf(rmax[0], rmax[1]), fmaxf(rmax[2], rmax[3]));

  float sum = 0.f;
#pragma unroll
  for (int i = 0; i < 8; ++i) { v[i] = __expf(v[i] - mx); sum += v[i]; }
#pragma unroll
  for (int off = 32; off >= 1; off >>= 1) sum += __shfl_xor(sum, off, 64);
  if (lane == 0) rsum[wv] = sum;
  __syncthreads();
  sum = rsum[0] + rsum[1] + rsum[2] + rsum[3];
  const float inv = 1.0f / sum;

  u16x8 o;
#pragma unroll
  for (int i = 0; i < 8; ++i) o[i] = f2bf(v[i] * inv);
  *(u16x8*)(po + tid * 8) = o;
}

extern "C" void kernel_launch(void* const* d_in, const int* in_sizes, int n_in,
                              void* d_out, int out_size, void* d_ws, size_t ws_size,
                              hipStream_t stream) {
  const float* hs = (const float*)d_in[0];
  const float* am = (const float*)d_in[1];
  const float* pm = (const float*)d_in[2];
  const float* Wq = (const float*)d_in[3];
  const float* bq = (const float*)d_in[4];
  const float* Wk = (const float*)d_in[5];
  const float* bk = (const float*)d_in[6];
  const float* Wv = (const float*)d_in[7];
  const float* bv = (const float*)d_in[8];
  const float* pw = (const float*)d_in[9];
  float* out = (float*)d_out;

  char* w = (char*)d_ws;
  u16* X      = (u16*)(w);                    // 16,777,216 B  (reused as Vt later)
  u16* Wqkv   = (u16*)(w + 16777216);         //  6,291,456 B
  float* bias = (float*)(w + 23068672);       //     12,288 B (pad to 16K)
  u16* Qb     = (u16*)(w + 23085056);         // 16,777,216 B
  u16* Kb     = (u16*)(w + 39862272);         // 16,777,216 B
  u16* Vb     = (u16*)(w + 56639488);         // 16,777,216 B
  float* sc   = (float*)(w + 73416704);       // 67,108,864 B (P bf16 in-place)
  u16* Vt     = X;                            // X dead after GEMM1
  u16* P      = (u16*)sc;

  // converts
  hipLaunchKernelGGL(f32_to_bf16_vec, dim3(8192), dim3(256), 0, stream, hs, X, 8388608L);
  hipLaunchKernelGGL(f32_to_bf16_vec, dim3(1024), dim3(256), 0, stream, Wq, Wqkv, 1048576L);
  hipLaunchKernelGGL(f32_to_bf16_vec, dim3(1024), dim3(256), 0, stream, Wk, Wqkv + 1048576, 1048576L);
  hipLaunchKernelGGL(f32_to_bf16_vec, dim3(1024), dim3(256), 0, stream, Wv, Wqkv + 2097152, 1048576L);
  hipLaunchKernelGGL(concat_bias, dim3(12), dim3(256), 0, stream, bq, bk, bv, bias);

  // GEMM1: X[8192,1024] @ Wqkv[3072,1024]^T -> Q,K,V bf16
  hipLaunchKernelGGL((gemm_bt<1>), dim3(24, 64, 1), dim3(256), 0, stream,
                     X, Wqkv, 1024, 1024, 1024, 0L, 0L,
                     (float*)nullptr, 0, 0L, Qb, Kb, Vb, bias);

  // V -> Vt
  hipLaunchKernelGGL(transpose_bf16, dim3(32, 64, 4), dim3(256), 0, stream, Vb, Vt);

  // GEMM2 (batched): scores[b] = Q[b] @ K[b]^T  (fp32)
  hipLaunchKernelGGL((gemm_bt<0>), dim3(16, 16, 4), dim3(256), 0, stream,
                     Qb, Kb, 1024, 1024, 1024, 2097152L, 2097152L,
                     sc, 2048, 4194304L,
                     (u16*)nullptr, (u16*)nullptr, (u16*)nullptr, (const float*)nullptr);

  // softmax rows (scale + masks fused), P bf16 in-place
  hipLaunchKernelGGL(softmax_rows, dim3(8192), dim3(256), 0, stream, sc, am, pm, pw, P);

  // GEMM3 (batched): out[b] = P[b] @ Vt[b]^T  (fp32)
  hipLaunchKernelGGL((gemm_bt<0>), dim3(8, 16, 4), dim3(256), 0, stream,
                     P, Vt, 2048, 4096, 2048, 8388608L, 2097152L,
                     out, 1024, 2097152L,
                     (u16*)nullptr, (u16*)nullptr, (u16*)nullptr, (const float*)nullptr);
}